// Round 1
// baseline (378.361 us; speedup 1.0000x reference)
//
#include <hip/hip_runtime.h>

// DigitCaps dynamic routing, all-f32.
// Shapes: x (512,1152,8), W (1152,10,16,8), out v (512,10,16).
// Never materialize u_hat (377MB). Per routing iter:
//   c = softmax_i(b)                       (tiny)
//   Wc[(i,s),(o,p)] = c[i,o]*W[i,o,p,s]    (rearrange+scale, 5.9MB)
//   s = x @ Wc                             (512 x 9216 x 160 GEMM, split-K partials)
//   v = squash(s)                          (fused with partial reduction)
//   G = x^T @ v                            (9216 x 512 x 160 GEMM, 2 batch-splits)
//   b += (1/512) * sum_{p,s} W .* G        (tiny contraction)

#define IC 1152
#define OC 10
#define PS 16
#define SS 8
#define NB 512
#define KD (IC * SS) /* 9216 */
#define ND (OC * PS) /* 160  */
#define NSPLIT 64
#define KPER (KD / NSPLIT) /* 144 */
#define KC 48

// ---------------- softmax over in-capsules (axis i), per column o ------------
__global__ void softmax_col(const float* __restrict__ bij, float* __restrict__ c)
{
    const int o = blockIdx.x;
    const int tid = threadIdx.x;
    __shared__ float red[256];

    float m = -3.4e38f;
    for (int i = tid; i < IC; i += 256) m = fmaxf(m, bij[i * OC + o]);
    red[tid] = m;
    __syncthreads();
    for (int st = 128; st > 0; st >>= 1) {
        if (tid < st) red[tid] = fmaxf(red[tid], red[tid + st]);
        __syncthreads();
    }
    m = red[0];
    __syncthreads();

    float sum = 0.f;
    for (int i = tid; i < IC; i += 256) sum += expf(bij[i * OC + o] - m);
    red[tid] = sum;
    __syncthreads();
    for (int st = 128; st > 0; st >>= 1) {
        if (tid < st) red[tid] += red[tid + st];
        __syncthreads();
    }
    const float inv = 1.0f / red[0];

    for (int i = tid; i < IC; i += 256)
        c[i * OC + o] = expf(bij[i * OC + o] - m) * inv;
}

// ---------------- Wc[(i*8+s)*160 + (o*16+p)] = c[i,o]*W[i,o,p,s] -------------
__global__ void make_wc(const float* __restrict__ W, const float* __restrict__ c,
                        float* __restrict__ wc)
{
    const int idx = blockIdx.x * 256 + threadIdx.x; // = k*160 + n
    const int k = idx / ND;
    const int n = idx - k * ND;
    const int i = k >> 3, s = k & 7;
    const int o = n >> 4, p = n & 15;
    wc[idx] = c[i * OC + o] * W[(((i * OC + o) * PS) + p) * SS + s];
}

// ---------------- GEMM1: part[ks] += x[64 rows] @ Wc  (split-K) --------------
__global__ __launch_bounds__(256) void gemm1_kernel(const float* __restrict__ x,
                                                    const float* __restrict__ wc,
                                                    float* __restrict__ part)
{
    __shared__ __align__(16) float xl[KC][68];   // [k][batch], pad 68 (bank shift 4)
    __shared__ __align__(16) float wl[KC][164];  // [k][n], pad 164

    const int tid = threadIdx.x;
    const int mb = blockIdx.x & 7;   // 8 tiles of 64 batch rows
    const int ks = blockIdx.x >> 3;  // 64 K-splits of 144
    const int m0 = mb * 64;
    const int cg = tid & 15, rg = tid >> 4;
    const int c0 = cg * 10, r0 = rg * 4;

    float acc[4][10] = {};

    for (int kc = 0; kc < KPER; kc += KC) {
        const int k0 = ks * KPER + kc;
        // stage x tile: 64 rows x 48 k, transposed into [k][batch]
        for (int q = tid; q < 768; q += 256) {
            const int r = q / 12;
            const int kv = q - r * 12;
            const float4 t = *(const float4*)(x + (size_t)(m0 + r) * KD + k0 + kv * 4);
            xl[kv * 4 + 0][r] = t.x;
            xl[kv * 4 + 1][r] = t.y;
            xl[kv * 4 + 2][r] = t.z;
            xl[kv * 4 + 3][r] = t.w;
        }
        // stage Wc tile: 48 k x 160 n (row-major)
        for (int q = tid; q < 1920; q += 256) {
            const int rr = q / 40;
            const int c4 = q - rr * 40;
            const float4 t = *(const float4*)(wc + (size_t)(k0 + rr) * ND + c4 * 4);
            *(float4*)&wl[rr][c4 * 4] = t;
        }
        __syncthreads();
#pragma unroll 4
        for (int kk = 0; kk < KC; ++kk) {
            const float4 a = *(const float4*)&xl[kk][r0];
            const float2 w0 = *(const float2*)&wl[kk][c0 + 0];
            const float2 w1 = *(const float2*)&wl[kk][c0 + 2];
            const float2 w2 = *(const float2*)&wl[kk][c0 + 4];
            const float2 w3 = *(const float2*)&wl[kk][c0 + 6];
            const float2 w4 = *(const float2*)&wl[kk][c0 + 8];
            const float av[4] = { a.x, a.y, a.z, a.w };
            const float wv[10] = { w0.x, w0.y, w1.x, w1.y, w2.x,
                                   w2.y, w3.x, w3.y, w4.x, w4.y };
#pragma unroll
            for (int r = 0; r < 4; ++r)
#pragma unroll
                for (int n = 0; n < 10; ++n)
                    acc[r][n] += av[r] * wv[n];
        }
        __syncthreads();
    }

    float* dst = part + (size_t)ks * (NB * ND);
#pragma unroll
    for (int r = 0; r < 4; ++r) {
        float* row = dst + (size_t)(m0 + r0 + r) * ND + c0;
#pragma unroll
        for (int n = 0; n < 10; ++n) row[n] = acc[r][n];
    }
}

// ---------------- reduce split-K partials + squash ---------------------------
__global__ void reduce_squash(const float* __restrict__ part, float* __restrict__ out)
{
    const int idx = blockIdx.x * blockDim.x + threadIdx.x; // b*10 + o
    if (idx >= NB * OC) return;

    float4 a0 = { 0, 0, 0, 0 }, a1 = a0, a2 = a0, a3 = a0;
    for (int sp = 0; sp < NSPLIT; ++sp) {
        const float4* p = (const float4*)(part + (size_t)sp * (NB * ND) + (size_t)idx * 16);
        const float4 p0 = p[0], p1 = p[1], p2 = p[2], p3 = p[3];
        a0.x += p0.x; a0.y += p0.y; a0.z += p0.z; a0.w += p0.w;
        a1.x += p1.x; a1.y += p1.y; a1.z += p1.z; a1.w += p1.w;
        a2.x += p2.x; a2.y += p2.y; a2.z += p2.z; a2.w += p2.w;
        a3.x += p3.x; a3.y += p3.y; a3.z += p3.z; a3.w += p3.w;
    }
    const float sq = a0.x * a0.x + a0.y * a0.y + a0.z * a0.z + a0.w * a0.w +
                     a1.x * a1.x + a1.y * a1.y + a1.z * a1.z + a1.w * a1.w +
                     a2.x * a2.x + a2.y * a2.y + a2.z * a2.z + a2.w * a2.w +
                     a3.x * a3.x + a3.y * a3.y + a3.z * a3.z + a3.w * a3.w;
    const float f = (sq / (1.0f + sq)) / sqrtf(sq + 1e-8f);
    a0.x *= f; a0.y *= f; a0.z *= f; a0.w *= f;
    a1.x *= f; a1.y *= f; a1.z *= f; a1.w *= f;
    a2.x *= f; a2.y *= f; a2.z *= f; a2.w *= f;
    a3.x *= f; a3.y *= f; a3.z *= f; a3.w *= f;
    float4* o4 = (float4*)(out + (size_t)idx * 16);
    o4[0] = a0; o4[1] = a1; o4[2] = a2; o4[3] = a3;
}

// ---------------- GEMM2: Gpart[bs][k,n] = sum_{b in half} x[b,k]*v[b,n] ------
__global__ __launch_bounds__(256) void gemm2_kernel(const float* __restrict__ x,
                                                    const float* __restrict__ v,
                                                    float* __restrict__ gpart)
{
    __shared__ __align__(16) float xl[64][68];   // [batch][k]
    __shared__ __align__(16) float vl[64][164];  // [batch][n]

    const int tid = threadIdx.x;
    int kt = blockIdx.x;
    int bs = 0;
    if (kt >= 144) { kt -= 144; bs = 1; }
    const int k0 = kt * 64;
    const int b0 = bs * 256;
    const int cg = tid & 15, rg = tid >> 4;
    const int c0 = cg * 10, r0 = rg * 4;

    float acc[4][10] = {};

    for (int bc = 0; bc < 256; bc += 64) {
        const int bb0 = b0 + bc;
        for (int q = tid; q < 1024; q += 256) {
            const int bb = q >> 4, kv = q & 15;
            const float4 t = *(const float4*)(x + (size_t)(bb0 + bb) * KD + k0 + kv * 4);
            *(float4*)&xl[bb][kv * 4] = t;
        }
        for (int q = tid; q < 2560; q += 256) {
            const int bb = q / 40;
            const int nv = q - bb * 40;
            const float4 t = *(const float4*)(v + (size_t)(bb0 + bb) * ND + nv * 4);
            *(float4*)&vl[bb][nv * 4] = t;
        }
        __syncthreads();
#pragma unroll 4
        for (int bb = 0; bb < 64; ++bb) {
            const float4 a = *(const float4*)&xl[bb][r0];
            const float2 w0 = *(const float2*)&vl[bb][c0 + 0];
            const float2 w1 = *(const float2*)&vl[bb][c0 + 2];
            const float2 w2 = *(const float2*)&vl[bb][c0 + 4];
            const float2 w3 = *(const float2*)&vl[bb][c0 + 6];
            const float2 w4 = *(const float2*)&vl[bb][c0 + 8];
            const float av[4] = { a.x, a.y, a.z, a.w };
            const float wv[10] = { w0.x, w0.y, w1.x, w1.y, w2.x,
                                   w2.y, w3.x, w3.y, w4.x, w4.y };
#pragma unroll
            for (int r = 0; r < 4; ++r)
#pragma unroll
                for (int n = 0; n < 10; ++n)
                    acc[r][n] += av[r] * wv[n];
        }
        __syncthreads();
    }

    float* dst = gpart + (size_t)bs * ((size_t)KD * ND);
#pragma unroll
    for (int r = 0; r < 4; ++r) {
        float* row = dst + (size_t)(k0 + r0 + r) * ND + c0;
#pragma unroll
        for (int n = 0; n < 10; ++n) row[n] = acc[r][n];
    }
}

// ---------------- b += (1/512) * sum_{p,s} W[i,o,p,s]*(G0+G1)[(i,s),(o,p)] ---
__global__ void agree_kernel(const float* __restrict__ W, const float* __restrict__ gpart,
                             float* __restrict__ bij)
{
    const int idx = blockIdx.x * blockDim.x + threadIdx.x; // i*10 + o
    if (idx >= IC * OC) return;
    const int i = idx / OC;
    const int o = idx - i * OC;
    const float* wp = W + (size_t)idx * (PS * SS);
    const float* g0 = gpart + (size_t)(i * SS) * ND + o * PS;
    const float* g1 = g0 + (size_t)KD * ND;

    float acc = 0.f;
    for (int p = 0; p < PS; ++p) {
#pragma unroll
        for (int s = 0; s < SS; ++s) {
            const float g = g0[s * ND + p] + g1[s * ND + p];
            acc += wp[p * SS + s] * g;
        }
    }
    bij[idx] += acc * (1.0f / 512.0f);
}

extern "C" void kernel_launch(void* const* d_in, const int* in_sizes, int n_in,
                              void* d_out, int out_size, void* d_ws, size_t ws_size,
                              hipStream_t stream)
{
    (void)in_sizes; (void)n_in; (void)out_size; (void)ws_size;
    const float* x = (const float*)d_in[0];
    const float* W = (const float*)d_in[1];
    float* out = (float*)d_out;
    float* ws = (float*)d_ws;

    // ws layout (floats): b_ij | c | Wc | partials(64*81920; G parts alias) | v
    float* b_ij = ws;                       // 11520
    float* cbuf = ws + 11520;               // 11520
    float* wcb  = ws + 23040;               // 1474560
    float* part = ws + 1497600;             // 5242880 (gemm2's 2x1474560 alias here)
    float* vbuf = ws + 6740480;             // 81920   (total 6822400 floats = 27.3MB)

    hipMemsetAsync(b_ij, 0, IC * OC * sizeof(float), stream);

    for (int it = 0; it < 3; ++it) {
        softmax_col<<<OC, 256, 0, stream>>>(b_ij, cbuf);
        make_wc<<<(KD * ND) / 256, 256, 0, stream>>>(W, cbuf, wcb);
        gemm1_kernel<<<NSPLIT * 8, 256, 0, stream>>>(x, wcb, part);
        reduce_squash<<<(NB * OC + 255) / 256, 256, 0, stream>>>(part, (it == 2) ? out : vbuf);
        if (it < 2) {
            gemm2_kernel<<<288, 256, 0, stream>>>(x, vbuf, part);
            agree_kernel<<<(IC * OC + 255) / 256, 256, 0, stream>>>(W, part, b_ij);
        }
    }
}

// Round 2
// 263.867 us; speedup vs baseline: 1.4339x; 1.4339x over previous
//
#include <hip/hip_runtime.h>

// DigitCaps dynamic routing, all-f32, restructured.
//   Wr[(i,s),(o,p)] precomputed once (no per-iter make_wc; c folded into gemm1 staging)
//   gemm1: s_part = x @ (c .* Wr), split-K 128, 128-row tiles, acc[8][10]
//   reduce_squash: 4-lane-per-(b,o) shfl reduction
//   gemm2_agree: G-tile contracted against Wr in epilogue -> atomicAdd b_ij (no G buffer)

#define IC 1152
#define OC 10
#define PS 16
#define SS 8
#define NB 512
#define KD (IC * SS) /* 9216 */
#define ND (OC * PS) /* 160  */

#define G1_BM 128
#define G1_NSPLIT 128
#define G1_KSP (KD / G1_NSPLIT) /* 72 */
#define G1_KC 36

#define G2_BCH 32
#define G2_NBS (NB / G2_BCH) /* 16 */
#define G2_NKT (KD / 64)     /* 144 */

// ---------------- Wr[(i*8+s)*160 + (o*16+p)] = W[i,o,p,s] (once) -------------
__global__ void prep_wr(const float* __restrict__ W, float* __restrict__ wr)
{
    const int q = blockIdx.x * 256 + threadIdx.x; // float4 index, 368640 total
    const int k = q / 40;
    const int n4 = q - k * 40;
    const int i = k >> 3, s = k & 7;
    const int o = n4 >> 2;          // (n4*4)>>4
    const int p0 = (n4 << 2) & 15;
    const float* wsrc = W + (((size_t)(i * OC + o) * PS) + p0) * SS + s;
    float4 t;
    t.x = wsrc[0]; t.y = wsrc[SS]; t.z = wsrc[2 * SS]; t.w = wsrc[3 * SS];
    *(float4*)(wr + (size_t)q * 4) = t;
}

// ---------------- softmax over in-capsules (axis i), per column o ------------
__global__ void softmax_col(const float* __restrict__ bij, float* __restrict__ c)
{
    const int o = blockIdx.x;
    const int tid = threadIdx.x;
    __shared__ float red[256];

    float m = -3.4e38f;
    for (int i = tid; i < IC; i += 256) m = fmaxf(m, bij[i * OC + o]);
    red[tid] = m;
    __syncthreads();
    for (int st = 128; st > 0; st >>= 1) {
        if (tid < st) red[tid] = fmaxf(red[tid], red[tid + st]);
        __syncthreads();
    }
    m = red[0];
    __syncthreads();

    float sum = 0.f;
    for (int i = tid; i < IC; i += 256) sum += expf(bij[i * OC + o] - m);
    red[tid] = sum;
    __syncthreads();
    for (int st = 128; st > 0; st >>= 1) {
        if (tid < st) red[tid] += red[tid + st];
        __syncthreads();
    }
    const float inv = 1.0f / red[0];

    for (int i = tid; i < IC; i += 256)
        c[i * OC + o] = expf(bij[i * OC + o] - m) * inv;
}

// ---------------- GEMM1: part[ks] = x[128 rows] @ (c .* Wr) ------------------
__global__ __launch_bounds__(256, 2) void gemm1_fused(const float* __restrict__ x,
                                                      const float* __restrict__ wr,
                                                      const float* __restrict__ c,
                                                      float* __restrict__ part)
{
    __shared__ __align__(16) float xl[G1_KC][G1_BM + 4]; // [k][row]
    __shared__ __align__(16) float wl[G1_KC][ND + 4];    // [k][n]
    __shared__ float cl[96];

    const int tid = threadIdx.x;
    const int mb = blockIdx.x & 3;  // 4 m-tiles of 128 rows
    const int ks = blockIdx.x >> 2; // 128 K-splits of 72
    const int m0 = mb * G1_BM;
    const int k0s = ks * G1_KSP;
    const int cg = tid & 15, rg = tid >> 4;
    const int c0 = cg * 10, r0 = rg * 8;

    // c-slice for this split: i0 = ks*9, 9 i's x 10 o = 90 floats
    if (tid < 90) cl[tid] = c ? c[ks * 90 + tid] : (1.0f / 1152.0f);
    __syncthreads();

    float acc[8][10] = {};

    for (int kc = 0; kc < G1_KSP; kc += G1_KC) {
        const int k0 = k0s + kc;
        // stage x tile transposed: 128 rows x 36 k
        for (int q = tid; q < (G1_BM * G1_KC / 4); q += 256) { // 1152
            const int r = q / 9, kv4 = q - r * 9;
            const float4 t = *(const float4*)(x + (size_t)(m0 + r) * KD + k0 + kv4 * 4);
            xl[kv4 * 4 + 0][r] = t.x;
            xl[kv4 * 4 + 1][r] = t.y;
            xl[kv4 * 4 + 2][r] = t.z;
            xl[kv4 * 4 + 3][r] = t.w;
        }
        // stage (c .* Wr) tile: 36 k x 160 n
        for (int q = tid; q < (G1_KC * 40); q += 256) { // 1440
            const int rr = q / 40, c4 = q - rr * 40;
            float4 t = *(const float4*)(wr + (size_t)(k0 + rr) * ND + c4 * 4);
            const float sc = cl[(((kc + rr) >> 3) * 10) + (c4 >> 2)];
            t.x *= sc; t.y *= sc; t.z *= sc; t.w *= sc;
            *(float4*)&wl[rr][c4 * 4] = t;
        }
        __syncthreads();
#pragma unroll 4
        for (int kk = 0; kk < G1_KC; ++kk) {
            const float4 a0 = *(const float4*)&xl[kk][r0];
            const float4 a1 = *(const float4*)&xl[kk][r0 + 4];
            const float2 w0 = *(const float2*)&wl[kk][c0 + 0];
            const float2 w1 = *(const float2*)&wl[kk][c0 + 2];
            const float2 w2 = *(const float2*)&wl[kk][c0 + 4];
            const float2 w3 = *(const float2*)&wl[kk][c0 + 6];
            const float2 w4 = *(const float2*)&wl[kk][c0 + 8];
            const float av[8] = { a0.x, a0.y, a0.z, a0.w, a1.x, a1.y, a1.z, a1.w };
            const float wv[10] = { w0.x, w0.y, w1.x, w1.y, w2.x,
                                   w2.y, w3.x, w3.y, w4.x, w4.y };
#pragma unroll
            for (int r = 0; r < 8; ++r)
#pragma unroll
                for (int n = 0; n < 10; ++n)
                    acc[r][n] += av[r] * wv[n];
        }
        __syncthreads();
    }

    float* dst = part + (size_t)ks * (NB * ND);
#pragma unroll
    for (int r = 0; r < 8; ++r) {
        float* row = dst + (size_t)(m0 + r0 + r) * ND + c0;
#pragma unroll
        for (int n = 0; n < 5; ++n)
            *(float2*)(row + n * 2) = *(const float2*)&acc[r][n * 2];
    }
}

// ---------------- reduce split-K partials + squash ---------------------------
__global__ void reduce_squash(const float* __restrict__ part, float* __restrict__ out)
{
    const int t = blockIdx.x * 128 + threadIdx.x; // 20480 = 512*10*4
    const int idx = t >> 2, q = t & 3;            // idx = b*10+o, q = p-quad
    const float* src = part + (size_t)idx * 16 + q * 4;
    float4 a = { 0, 0, 0, 0 };
#pragma unroll 8
    for (int sp = 0; sp < G1_NSPLIT; ++sp) {
        const float4 p = *(const float4*)(src + (size_t)sp * (NB * ND));
        a.x += p.x; a.y += p.y; a.z += p.z; a.w += p.w;
    }
    float sq = a.x * a.x + a.y * a.y + a.z * a.z + a.w * a.w;
    sq += __shfl_xor(sq, 1);
    sq += __shfl_xor(sq, 2);
    const float f = (sq / (1.0f + sq)) / sqrtf(sq + 1e-8f);
    a.x *= f; a.y *= f; a.z *= f; a.w *= f;
    *(float4*)(out + (size_t)idx * 16 + q * 4) = a;
}

// ---------------- GEMM2+agree: b_ij += (1/512) sum W .* (x^T v) --------------
__global__ __launch_bounds__(128, 2) void gemm2_agree(const float* __restrict__ x,
                                                      const float* __restrict__ v,
                                                      const float* __restrict__ wr,
                                                      float* __restrict__ bij)
{
    __shared__ __align__(16) float xl[G2_BCH][68];  // [batch][k (64)]
    __shared__ __align__(16) float vl[G2_BCH][164]; // [batch][n (160)]
    __shared__ float agr[80];

    const int tid = threadIdx.x;
    const int kt = blockIdx.x % G2_NKT; // 144 k-tiles of 64
    const int bs = blockIdx.x / G2_NKT; // 16 batch chunks of 32
    const int k0 = kt * 64, b0 = bs * G2_BCH;
    const int cg = tid & 15, rg = tid >> 4; // rg 0..7
    const int c0 = cg * 10, r0 = rg * 8;

    if (tid < 80) agr[tid] = 0.f;

    for (int q = tid; q < G2_BCH * 16; q += 128) { // 512
        const int bb = q >> 4, kv = q & 15;
        *(float4*)&xl[bb][kv * 4] = *(const float4*)(x + (size_t)(b0 + bb) * KD + k0 + kv * 4);
    }
    for (int q = tid; q < G2_BCH * 40; q += 128) { // 1280
        const int bb = q / 40, nv = q - bb * 40;
        *(float4*)&vl[bb][nv * 4] = *(const float4*)(v + (size_t)(b0 + bb) * ND + nv * 4);
    }
    __syncthreads();

    float acc[8][10] = {};
#pragma unroll 4
    for (int bb = 0; bb < G2_BCH; ++bb) {
        const float4 a0 = *(const float4*)&xl[bb][r0];
        const float4 a1 = *(const float4*)&xl[bb][r0 + 4];
        const float2 w0 = *(const float2*)&vl[bb][c0 + 0];
        const float2 w1 = *(const float2*)&vl[bb][c0 + 2];
        const float2 w2 = *(const float2*)&vl[bb][c0 + 4];
        const float2 w3 = *(const float2*)&vl[bb][c0 + 6];
        const float2 w4 = *(const float2*)&vl[bb][c0 + 8];
        const float av[8] = { a0.x, a0.y, a0.z, a0.w, a1.x, a1.y, a1.z, a1.w };
        const float wv[10] = { w0.x, w0.y, w1.x, w1.y, w2.x,
                               w2.y, w3.x, w3.y, w4.x, w4.y };
#pragma unroll
        for (int r = 0; r < 8; ++r)
#pragma unroll
            for (int n = 0; n < 10; ++n)
                acc[r][n] += av[r] * wv[n];
    }

    // epilogue: contract G-tile with Wr, reduce to (i_local=rg, o) pairs
    const int o0 = c0 >> 4;
    const int nsp = (o0 + 1) * 16 - c0; // 1..16: first cols belong to o0
    float sum0 = 0.f, sum1 = 0.f;
#pragma unroll
    for (int r = 0; r < 8; ++r) {
        const float* wrow = wr + (size_t)(k0 + r0 + r) * ND + c0;
#pragma unroll
        for (int n = 0; n < 10; ++n) {
            const float t = acc[r][n] * wrow[n];
            if (n < nsp) sum0 += t; else sum1 += t;
        }
    }
    atomicAdd(&agr[rg * 10 + o0], sum0);
    if (nsp < 10) atomicAdd(&agr[rg * 10 + o0 + 1], sum1);
    __syncthreads();

    if (tid < 80) atomicAdd(bij + kt * 80 + tid, agr[tid] * (1.0f / 512.0f));
}

extern "C" void kernel_launch(void* const* d_in, const int* in_sizes, int n_in,
                              void* d_out, int out_size, void* d_ws, size_t ws_size,
                              hipStream_t stream)
{
    (void)in_sizes; (void)n_in; (void)out_size; (void)ws_size;
    const float* x = (const float*)d_in[0];
    const float* W = (const float*)d_in[1];
    float* out = (float*)d_out;
    float* ws = (float*)d_ws;

    // ws layout (floats)
    float* b_ij = ws;            // 11520
    float* cbuf = ws + 11520;    // 11520
    float* wrb  = ws + 23040;    // 1474560
    float* part = ws + 1497600;  // 128*81920 = 10485760
    float* vbuf = ws + 11983360; // 81920  (total 12065280 floats = 48.3MB)

    hipMemsetAsync(b_ij, 0, IC * OC * sizeof(float), stream);
    prep_wr<<<1440, 256, 0, stream>>>(W, wrb);

    for (int it = 0; it < 3; ++it) {
        const float* cptr = nullptr;
        if (it > 0) {
            softmax_col<<<OC, 256, 0, stream>>>(b_ij, cbuf);
            cptr = cbuf;
        }
        gemm1_fused<<<G1_NSPLIT * 4, 256, 0, stream>>>(x, wrb, cptr, part);
        reduce_squash<<<160, 128, 0, stream>>>(part, (it == 2) ? out : vbuf);
        if (it < 2)
            gemm2_agree<<<G2_NKT * G2_NBS, 128, 0, stream>>>(x, vbuf, wrb, b_ij);
    }
}